// Round 5
// baseline (449.106 us; speedup 1.0000x reference)
//
#include <hip/hip_runtime.h>
#include <math.h>

// Problem constants
constexpr int CB = 8;      // batch
constexpr int CS = 1024;   // seq
constexpr int CD = 512;    // model dim
constexpr int CH = 8;      // heads
constexpr int CHD = 64;    // head dim
constexpr int CDFF = 2048; // ffn dim
constexpr int NROW = CB * CS;

typedef unsigned short u16;
typedef unsigned int u32;
typedef unsigned char u8;
typedef __attribute__((ext_vector_type(8))) short short8;
typedef __attribute__((ext_vector_type(8))) unsigned short ushort8v;
typedef __attribute__((ext_vector_type(4))) float floatx4;

__device__ inline u16 f2bf(float f) {
    union { float f; unsigned u; } v; v.f = f;
    unsigned u = v.u + 0x7FFFu + ((v.u >> 16) & 1u);  // RNE
    return (u16)(u >> 16);
}
__device__ inline float bf2f(u16 h) {
    union { unsigned u; float f; } v; v.u = ((unsigned)h) << 16;
    return v.f;
}

// async global->LDS, 16B per lane; LDS dest is wave-uniform base + lane*16
__device__ inline void gload16(const u16* g, u16* l) {
    __builtin_amdgcn_global_load_lds(
        (const __attribute__((address_space(1))) u32*)g,
        (__attribute__((address_space(3))) u32*)l, 16, 0, 0);
}

// ---------------------------------------------------------------------------
// LayerNorm (+ optional embedding add). One block per row, 256 threads.
// ---------------------------------------------------------------------------
__global__ __launch_bounds__(256) void ln_kernel(
    const float* __restrict__ x, const int* __restrict__ ids,
    const float* __restrict__ emb,
    const float* __restrict__ g, const float* __restrict__ beta,
    float* __restrict__ xr_out, u16* __restrict__ xn_out)
{
    __shared__ float red1[4], red2[4];
    __shared__ float mu_s, ri_s;
    int row = blockIdx.x;
    int tid = threadIdx.x;
    int d0 = tid * 2;
    const float* xrow = x + (size_t)row * CD;
    float2 xv = *(const float2*)(xrow + d0);
    float v0 = xv.x, v1 = xv.y;
    if (emb) {
        int id = ids[row];
        float2 ev = *(const float2*)(emb + (size_t)id * CD + d0);
        v0 += ev.x; v1 += ev.y;
    }
    float s1 = v0 + v1;
    float s2 = v0 * v0 + v1 * v1;
    for (int off = 32; off > 0; off >>= 1) {
        s1 += __shfl_down(s1, off, 64);
        s2 += __shfl_down(s2, off, 64);
    }
    int wave = tid >> 6;
    if ((tid & 63) == 0) { red1[wave] = s1; red2[wave] = s2; }
    __syncthreads();
    if (tid == 0) {
        float t1 = red1[0] + red1[1] + red1[2] + red1[3];
        float t2 = red2[0] + red2[1] + red2[2] + red2[3];
        float mu = t1 / CD;
        float var = t2 / CD - mu * mu;
        mu_s = mu;
        ri_s = rsqrtf(var + 1e-5f);
    }
    __syncthreads();
    float mu = mu_s, ri = ri_s;
    if (xr_out) {
        float2 o; o.x = v0; o.y = v1;
        *(float2*)(xr_out + (size_t)row * CD + d0) = o;
    }
    float2 gv = *(const float2*)(g + d0);
    float2 bv = *(const float2*)(beta + d0);
    float n0 = (v0 - mu) * ri * gv.x + bv.x;
    float n1 = (v1 - mu) * ri * gv.y + bv.y;
    u32 pk = (u32)f2bf(n0) | ((u32)f2bf(n1) << 16);
    *(u32*)(xn_out + (size_t)row * CD + d0) = pk;
}

// ---------------------------------------------------------------------------
// fp32 -> bf16 elementwise convert (weights), 8 elems/thread
// ---------------------------------------------------------------------------
__global__ __launch_bounds__(256) void conv_kernel(
    const float* __restrict__ src, u16* __restrict__ dst)
{
    size_t i = ((size_t)blockIdx.x * 256 + threadIdx.x) * 8;
    float4 a = *(const float4*)(src + i);
    float4 b = *(const float4*)(src + i + 4);
    ushort8v o;
    o[0] = f2bf(a.x); o[1] = f2bf(a.y); o[2] = f2bf(a.z); o[3] = f2bf(a.w);
    o[4] = f2bf(b.x); o[5] = f2bf(b.y); o[6] = f2bf(b.z); o[7] = f2bf(b.w);
    *(ushort8v*)(dst + i) = o;
}

// ---------------------------------------------------------------------------
// bf16 MFMA GEMM (m97 recipe): C[M,N] = act(A[M,K] @ W[N,K]^T + bias)(+res)
// ---------------------------------------------------------------------------
template <int ACT, int RES, int OUTBF>
__global__ __launch_bounds__(256) void gemm_mfma(
    const u16* __restrict__ A, const u16* __restrict__ W,
    const float* __restrict__ bias, const float* __restrict__ res,
    void* __restrict__ Cout, int M, int N, int K)
{
    __shared__ u16 As[128 * 32];
    __shared__ u16 Bs[128 * 32];
    int t = threadIdx.x;
    int lane = t & 63;
    int w = t >> 6;
    int m0 = blockIdx.x * 128;
    int n0 = blockIdx.y * 128;
    int col = lane & 15;
    int quad = lane >> 4;
    int wm = w & 1, wn = w >> 1;

    const u16* ag = A + (size_t)(m0 + (t >> 2)) * K + (t & 3) * 8;
    const u16* ag2 = ag + (size_t)64 * K;
    const u16* bg = W + (size_t)(n0 + (t >> 2)) * K + (t & 3) * 8;
    const u16* bg2 = bg + (size_t)64 * K;
    u16* la = As + w * 512;
    u16* lb = Bs + w * 512;

    floatx4 acc[4][4];
#pragma unroll
    for (int i = 0; i < 4; i++)
#pragma unroll
        for (int j = 0; j < 4; j++) acc[i][j] = (floatx4){0.f, 0.f, 0.f, 0.f};

    for (int kt = 0; kt < K; kt += 32) {
        gload16(ag + kt, la);
        gload16(ag2 + kt, la + 2048);
        gload16(bg + kt, lb);
        gload16(bg2 + kt, lb + 2048);
        __syncthreads();
        short8 af[4], bf[4];
#pragma unroll
        for (int mi = 0; mi < 4; mi++)
            af[mi] = *(const short8*)&As[(wm * 64 + mi * 16 + col) * 32 + quad * 8];
#pragma unroll
        for (int ni = 0; ni < 4; ni++)
            bf[ni] = *(const short8*)&Bs[(wn * 64 + ni * 16 + col) * 32 + quad * 8];
#pragma unroll
        for (int mi = 0; mi < 4; mi++)
#pragma unroll
            for (int ni = 0; ni < 4; ni++)
                acc[mi][ni] = __builtin_amdgcn_mfma_f32_16x16x32_bf16(
                    af[mi], bf[ni], acc[mi][ni], 0, 0, 0);
        __syncthreads();
    }

#pragma unroll
    for (int mi = 0; mi < 4; mi++)
#pragma unroll
        for (int ni = 0; ni < 4; ni++) {
            int c = n0 + wn * 64 + ni * 16 + col;
            float bv = bias[c];
#pragma unroll
            for (int r = 0; r < 4; r++) {
                int m = m0 + wm * 64 + mi * 16 + quad * 4 + r;
                float v = acc[mi][ni][r] + bv;
                if (ACT == 1) v = 0.5f * v * (1.0f + erff(v * 0.70710678118654752f));
                if (RES) v += res[(size_t)m * N + c];
                if (OUTBF) ((u16*)Cout)[(size_t)m * N + c] = f2bf(v);
                else       ((float*)Cout)[(size_t)m * N + c] = v;
            }
        }
}

// ---------------------------------------------------------------------------
// V bf16 (in qkv [B,S,1536] @ col 1024..) -> vt bf16 [B,H,64,S] transposed
// ---------------------------------------------------------------------------
__global__ __launch_bounds__(256) void vt_kernel(
    const u16* __restrict__ qkvb, u16* __restrict__ vt)
{
    __shared__ u16 tile[64][72];
    int b = blockIdx.x >> 4;
    int s0 = (blockIdx.x & 15) * 64;
    int h = blockIdx.y;
    int t = threadIdx.x;
    int r = t >> 2;
    int c0 = (t & 3) * 16;
    const u16* src = qkvb + (size_t)(b * CS + s0 + r) * 1536 + 2 * CD + h * CHD + c0;
    *(ushort8v*)&tile[r][c0] = *(const ushort8v*)src;
    *(ushort8v*)&tile[r][c0 + 8] = *(const ushort8v*)(src + 8);
    __syncthreads();
    u16* dst = vt + (((size_t)b * CH + h) * CHD + r) * CS + s0 + c0;
    ushort8v lo, hi;
#pragma unroll
    for (int j = 0; j < 8; j++) { lo[j] = tile[c0 + j][r]; hi[j] = tile[c0 + 8 + j][r]; }
    *(ushort8v*)dst = lo;
    *(ushort8v*)(dst + 8) = hi;
}

// ---------------------------------------------------------------------------
// Attention kernel A: grid (b*16 + qt, h) = (128, 8) -> 1024 blocks, 4 waves.
// Wave w owns q rows [qt*64 + w*16, +16) for head h. ZERO barriers (per-wave
// LDS only). Pass1: QK^T MFMA + exp -> rowsums (shfl reduce) -> 1/L.
// Pass2: recompute QK^T, p = e/L; p -> per-wave LDS (bf16, A-frag order) for
// PV MFMA; p*64 -> pbuf as manual e4m3 bytes (layout [b][q][h][kperm],
// kperm = kt*64 + col*4 + ni, true k = kt*64 + ni*16 + col).
// PV: V^T B-frags 16B-contig from vt; O = 4 C-frags (16q x 64d); ctx bf16.
// ---------------------------------------------------------------------------
__global__ __launch_bounds__(256, 4) void attn_mfma_kernel(
    const u16* __restrict__ qkvb, const u16* __restrict__ vt,
    u16* __restrict__ ctx, u8* __restrict__ pbuf)
{
    __shared__ u16 S[4][16][72];   // per-wave p tile (16 q x 64 k, +pad)

    int tid = threadIdx.x;
    int lane = tid & 63;
    int w = tid >> 6;
    int b = blockIdx.x >> 4;
    int q0 = (blockIdx.x & 15) * 64 + w * 16;
    int h = blockIdx.y;
    int col = lane & 15;
    int quad = lane >> 4;

    const u16* qkb = qkvb + (size_t)b * CS * 1536;
    const u16* qrow = qkb + (size_t)(q0 + col) * 1536 + h * CHD + quad * 8;
    short8 qa0 = *(const short8*)qrow;
    short8 qa1 = *(const short8*)(qrow + 32);

    // ---- pass 1: rowsums of e = exp(s/8) ----
    float esum[4] = {0.f, 0.f, 0.f, 0.f};
    for (int kt = 0; kt < 16; kt++) {
        int key0 = kt * 64;
        floatx4 c[4];
#pragma unroll
        for (int ni = 0; ni < 4; ni++) {
            const u16* krow = qkb + (size_t)(key0 + ni * 16 + col) * 1536 + CD + h * CHD + quad * 8;
            short8 kb0 = *(const short8*)krow;
            short8 kb1 = *(const short8*)(krow + 32);
            floatx4 cc = {0.f, 0.f, 0.f, 0.f};
            cc = __builtin_amdgcn_mfma_f32_16x16x32_bf16(qa0, kb0, cc, 0, 0, 0);
            cc = __builtin_amdgcn_mfma_f32_16x16x32_bf16(qa1, kb1, cc, 0, 0, 0);
            c[ni] = cc;
        }
#pragma unroll
        for (int ni = 0; ni < 4; ni++)
#pragma unroll
            for (int r = 0; r < 4; r++)
                esum[r] += __expf(c[ni][r] * 0.125f);
    }
#pragma unroll
    for (int r = 0; r < 4; r++) {
        esum[r] += __shfl_xor(esum[r], 1, 64);
        esum[r] += __shfl_xor(esum[r], 2, 64);
        esum[r] += __shfl_xor(esum[r], 4, 64);
        esum[r] += __shfl_xor(esum[r], 8, 64);
    }
    float li[4];
#pragma unroll
    for (int r = 0; r < 4; r++) li[r] = 1.0f / esum[r];

    // ---- pass 2: p = e/L -> LDS (PV) + pbuf (e4m3 bytes) ; PV MFMA ----
    u16* Sw = &S[w][0][0];
    floatx4 o[4];
#pragma unroll
    for (int d = 0; d < 4; d++) o[d] = (floatx4){0.f, 0.f, 0.f, 0.f};

    u8* pb = pbuf + ((size_t)(b * CS + q0 + quad * 4) * CH + h) * CS + col * 4;
    const size_t prstride = (size_t)CH * CS;   // q-row stride in bytes

    for (int kt = 0; kt < 16; kt++) {
        int key0 = kt * 64;
        float e[4][4];
#pragma unroll
        for (int ni = 0; ni < 4; ni++) {
            const u16* krow = qkb + (size_t)(key0 + ni * 16 + col) * 1536 + CD + h * CHD + quad * 8;
            short8 kb0 = *(const short8*)krow;
            short8 kb1 = *(const short8*)(krow + 32);
            floatx4 cc = {0.f, 0.f, 0.f, 0.f};
            cc = __builtin_amdgcn_mfma_f32_16x16x32_bf16(qa0, kb0, cc, 0, 0, 0);
            cc = __builtin_amdgcn_mfma_f32_16x16x32_bf16(qa1, kb1, cc, 0, 0, 0);
#pragma unroll
            for (int r = 0; r < 4; r++)
                e[ni][r] = __expf(cc[r] * 0.125f) * li[r];
        }
        // LDS p (bf16 truncation), true-k order: S[q][ni*16+col]
#pragma unroll
        for (int ni = 0; ni < 4; ni++)
#pragma unroll
            for (int r = 0; r < 4; r++) {
                union { float f; u32 u; } pu; pu.f = e[ni][r];
                Sw[(quad * 4 + r) * 72 + ni * 16 + col] = (u16)(pu.u >> 16);
            }
        // pbuf e4m3 bytes of p*64, packed 4 ni per u32 at kperm = col*4+ni
#pragma unroll
        for (int r = 0; r < 4; r++) {
            u32 pk = 0;
#pragma unroll
            for (int ni = 0; ni < 4; ni++) {
                union { float f; u32 u; } yu; yu.f = e[ni][r] * 64.f;
                u32 u = yu.u + 0x00080000u + ((yu.u >> 20) & 1u);  // RNE to 3 mant
                int e8 = (int)(u >> 23) - 120;                      // bias 127->7
                u32 byte = (e8 <= 0) ? 0u : (u32)((e8 << 3) | ((u >> 20) & 7u));
                pk |= byte << (ni * 8);
            }
            *(u32*)(pb + (size_t)r * prstride + key0) = pk;
        }
        // PV: o[dblk] += p(16q x 64k) @ V^T(64k x 16d)
        short8 pa0 = *(const short8*)&Sw[col * 72 + quad * 8];
        short8 pa1 = *(const short8*)&Sw[col * 72 + 32 + quad * 8];
#pragma unroll
        for (int dblk = 0; dblk < 4; dblk++) {
            const u16* vrow = vt + (((size_t)b * CH + h) * CHD + dblk * 16 + col) * CS + key0 + quad * 8;
            short8 vb0 = *(const short8*)vrow;
            short8 vb1 = *(const short8*)(vrow + 32);
            o[dblk] = __builtin_amdgcn_mfma_f32_16x16x32_bf16(pa0, vb0, o[dblk], 0, 0, 0);
            o[dblk] = __builtin_amdgcn_mfma_f32_16x16x32_bf16(pa1, vb1, o[dblk], 0, 0, 0);
        }
    }

    // ctx write: C-frag rows quad*4+r, cols dblk*16+col (bf16)
    u16* cb = ctx + ((size_t)(b * CS) + q0) * CD + h * CHD;
#pragma unroll
    for (int dblk = 0; dblk < 4; dblk++)
#pragma unroll
        for (int r = 0; r < 4; r++)
            cb[(size_t)(quad * 4 + r) * CD + dblk * 16 + col] = f2bf(o[dblk][r]);
}

// ---------------------------------------------------------------------------
// Attention kernel B: aw = (1/8) * sum_h p  from pbuf e4m3 bytes.
// Block per (b,q): 8192 blocks; thread t reads u32 (4 bytes) per head plane.
// kperm -> true k: u32 at offset t*4 holds ni=0..3 for (T=t>>4, col=t&15),
// true k = T*64 + ni*16 + col.
// ---------------------------------------------------------------------------
__global__ __launch_bounds__(256) void aw_reduce_kernel(
    const u8* __restrict__ pbuf, float* __restrict__ aw_out)
{
    int t = threadIdx.x;
    size_t bq = blockIdx.x;
    const u32* base = (const u32*)(pbuf + bq * CH * CS);
    float s[4] = {0.f, 0.f, 0.f, 0.f};
#pragma unroll
    for (int h = 0; h < CH; h++) {
        u32 v = base[h * (CS / 4) + t];
#pragma unroll
        for (int j = 0; j < 4; j++) {
            u32 byte = (v >> (j * 8)) & 255u;
            union { u32 u; float f; } d; d.u = (byte << 20) + 0x3C000000u;
            s[j] += byte ? d.f : 0.f;
        }
    }
    int T = t >> 4, col = t & 15;
    float* awp = aw_out + bq * CS + T * 64 + col;
#pragma unroll
    for (int j = 0; j < 4; j++) awp[(size_t)j * 16] = s[j] * (1.0f / 512.0f);
}

// ---------------------------------------------------------------------------
extern "C" void kernel_launch(void* const* d_in, const int* in_sizes, int n_in,
                              void* d_out, int out_size, void* d_ws, size_t ws_size,
                              hipStream_t stream)
{
    const float* x    = (const float*)d_in[0];
    const int*   ids  = (const int*)d_in[1];
    const float* emb  = (const float*)d_in[2];
    const float* inw  = (const float*)d_in[3];
    const float* inb  = (const float*)d_in[4];
    const float* ow   = (const float*)d_in[5];
    const float* ob   = (const float*)d_in[6];
    const float* g1   = (const float*)d_in[7];
    const float* be1  = (const float*)d_in[8];
    const float* g2   = (const float*)d_in[9];
    const float* be2  = (const float*)d_in[10];
    const float* w1   = (const float*)d_in[11];
    const float* b1   = (const float*)d_in[12];
    const float* w2   = (const float*)d_in[13];
    const float* b2   = (const float*)d_in[14];

    float* out_x  = (float*)d_out;
    float* out_aw = out_x + (size_t)CB * CS * CD;

    // Workspace layout. ZONE is time-shared: pbuf lives only between kernels
    // A and B; xnb/x2/hidb/weights occupy the same bytes outside that window
    // (weight convs for ow/w1/w2 are launched AFTER kernel B).
    char* p = (char*)d_ws;
    float* xr   = (float*)p; p += (size_t)NROW * CD * 4;              // 16 MB
    u16* qkvb   = (u16*)p;   p += (size_t)NROW * 3 * CD * 2;          // 24 MB
    u16* ctxb   = (u16*)p;   p += (size_t)NROW * CD * 2;              //  8 MB
    u16* vtb    = (u16*)p;   p += (size_t)CB * CH * CHD * CS * 2;     // 16 MB
    char* zone  = p;                                                  // 67 MB zone
    u8*  pbuf   = (u8*)zone;                                          // [A..B] 64 MB
    char* z = zone;
    u16* xnb    = (u16*)z;   z += (size_t)NROW * CD * 2;              //  8 MB
    float* x2   = (float*)z; z += (size_t)NROW * CD * 4;              // 16 MB
    u16* hidb   = (u16*)z;   z += (size_t)NROW * CDFF * 2;            // 32 MB
    u16* inwb   = (u16*)z;   z += (size_t)3 * CD * CD * 2;            //  3 MB
    u16* owb    = (u16*)z;   z += (size_t)CD * CD * 2;
    u16* w1b    = (u16*)z;   z += (size_t)CDFF * CD * 2;
    u16* w2b    = (u16*)z;   z += (size_t)CD * CDFF * 2;

    dim3 blk(256);
    // inwb needed before attention window; dead after qkv GEMM
    conv_kernel<<<(3 * CD * CD) / 2048, blk, 0, stream>>>(inw, inwb);
    // 1) x+emb, LN1 -> xr fp32, xnb bf16
    ln_kernel<<<NROW, blk, 0, stream>>>(x, ids, emb, g1, be1, xr, xnb);
    // 2) qkv projection (bf16 MFMA, bf16 out)
    gemm_mfma<0, 0, 1><<<dim3(NROW / 128, (3 * CD) / 128), blk, 0, stream>>>(
        xnb, inwb, inb, nullptr, qkvb, NROW, 3 * CD, CD);
    // 3a) V transpose
    vt_kernel<<<dim3(CB * (CS / 64), CH), blk, 0, stream>>>(qkvb, vtb);
    // 3b) attention A: ctx + pbuf (clobbers xnb/x2/hidb/weights zone)
    attn_mfma_kernel<<<dim3(CB * 16, CH), blk, 0, stream>>>(qkvb, vtb, ctxb, pbuf);
    // 3c) attention B: head-averaged weights from pbuf
    aw_reduce_kernel<<<CB * CS, blk, 0, stream>>>(pbuf, out_aw);
    // weight conversions for the post-attention GEMMs (zone now free)
    conv_kernel<<<(CD * CD) / 2048, blk, 0, stream>>>(ow, owb);
    conv_kernel<<<(CDFF * CD) / 2048, blk, 0, stream>>>(w1, w1b);
    conv_kernel<<<(CD * CDFF) / 2048, blk, 0, stream>>>(w2, w2b);
    // 4) out projection + residual -> x2 fp32
    gemm_mfma<0, 1, 0><<<dim3(NROW / 128, CD / 128), blk, 0, stream>>>(
        ctxb, owb, ob, xr, x2, NROW, CD, CD);
    // 5) LN2 -> xnb bf16
    ln_kernel<<<NROW, blk, 0, stream>>>(x2, nullptr, nullptr, g2, be2, nullptr, xnb);
    // 6) FFN up + exact GELU -> hidb bf16
    gemm_mfma<1, 0, 1><<<dim3(NROW / 128, CDFF / 128), blk, 0, stream>>>(
        xnb, w1b, b1, nullptr, hidb, NROW, CDFF, CD);
    // 7) FFN down + bias + residual -> output fp32
    gemm_mfma<0, 1, 0><<<dim3(NROW / 128, CD / 128), blk, 0, stream>>>(
        hidb, w2b, b2, x2, out_x, NROW, CD, CDFF);
}

// Round 6
// 411.704 us; speedup vs baseline: 1.0908x; 1.0908x over previous
//
#include <hip/hip_runtime.h>
#include <math.h>

// Problem constants
constexpr int CB = 8;      // batch
constexpr int CS = 1024;   // seq
constexpr int CD = 512;    // model dim
constexpr int CH = 8;      // heads
constexpr int CHD = 64;    // head dim
constexpr int CDFF = 2048; // ffn dim
constexpr int NROW = CB * CS;

typedef unsigned short u16;
typedef unsigned int u32;
typedef __attribute__((ext_vector_type(8))) short short8;
typedef __attribute__((ext_vector_type(8))) unsigned short ushort8v;
typedef __attribute__((ext_vector_type(4))) float floatx4;

__device__ inline u16 f2bf(float f) {
    union { float f; unsigned u; } v; v.f = f;
    unsigned u = v.u + 0x7FFFu + ((v.u >> 16) & 1u);  // RNE
    return (u16)(u >> 16);
}
__device__ inline float bf2f(u16 h) {
    union { unsigned u; float f; } v; v.u = ((unsigned)h) << 16;
    return v.f;
}

// async global->LDS, 16B per lane; LDS dest is wave-uniform base + lane*16
__device__ inline void gload16(const u16* g, u16* l) {
    __builtin_amdgcn_global_load_lds(
        (const __attribute__((address_space(1))) u32*)g,
        (__attribute__((address_space(3))) u32*)l, 16, 0, 0);
}

// ---------------------------------------------------------------------------
// LayerNorm (+ optional embedding add). One block per row, 256 threads.
// ---------------------------------------------------------------------------
__global__ __launch_bounds__(256) void ln_kernel(
    const float* __restrict__ x, const int* __restrict__ ids,
    const float* __restrict__ emb,
    const float* __restrict__ g, const float* __restrict__ beta,
    float* __restrict__ xr_out, u16* __restrict__ xn_out)
{
    __shared__ float red1[4], red2[4];
    __shared__ float mu_s, ri_s;
    int row = blockIdx.x;
    int tid = threadIdx.x;
    int d0 = tid * 2;
    const float* xrow = x + (size_t)row * CD;
    float2 xv = *(const float2*)(xrow + d0);
    float v0 = xv.x, v1 = xv.y;
    if (emb) {
        int id = ids[row];
        float2 ev = *(const float2*)(emb + (size_t)id * CD + d0);
        v0 += ev.x; v1 += ev.y;
    }
    float s1 = v0 + v1;
    float s2 = v0 * v0 + v1 * v1;
    for (int off = 32; off > 0; off >>= 1) {
        s1 += __shfl_down(s1, off, 64);
        s2 += __shfl_down(s2, off, 64);
    }
    int wave = tid >> 6;
    if ((tid & 63) == 0) { red1[wave] = s1; red2[wave] = s2; }
    __syncthreads();
    if (tid == 0) {
        float t1 = red1[0] + red1[1] + red1[2] + red1[3];
        float t2 = red2[0] + red2[1] + red2[2] + red2[3];
        float mu = t1 / CD;
        float var = t2 / CD - mu * mu;
        mu_s = mu;
        ri_s = rsqrtf(var + 1e-5f);
    }
    __syncthreads();
    float mu = mu_s, ri = ri_s;
    if (xr_out) {
        float2 o; o.x = v0; o.y = v1;
        *(float2*)(xr_out + (size_t)row * CD + d0) = o;
    }
    float2 gv = *(const float2*)(g + d0);
    float2 bv = *(const float2*)(beta + d0);
    float n0 = (v0 - mu) * ri * gv.x + bv.x;
    float n1 = (v1 - mu) * ri * gv.y + bv.y;
    u32 pk = (u32)f2bf(n0) | ((u32)f2bf(n1) << 16);
    *(u32*)(xn_out + (size_t)row * CD + d0) = pk;
}

// ---------------------------------------------------------------------------
// fp32 -> bf16 elementwise convert (weights), 8 elems/thread
// ---------------------------------------------------------------------------
__global__ __launch_bounds__(256) void conv_kernel(
    const float* __restrict__ src, u16* __restrict__ dst)
{
    size_t i = ((size_t)blockIdx.x * 256 + threadIdx.x) * 8;
    float4 a = *(const float4*)(src + i);
    float4 b = *(const float4*)(src + i + 4);
    ushort8v o;
    o[0] = f2bf(a.x); o[1] = f2bf(a.y); o[2] = f2bf(a.z); o[3] = f2bf(a.w);
    o[4] = f2bf(b.x); o[5] = f2bf(b.y); o[6] = f2bf(b.z); o[7] = f2bf(b.w);
    *(ushort8v*)(dst + i) = o;
}

// ---------------------------------------------------------------------------
// bf16 MFMA GEMM, 128x128 tile (m97 recipe): C = act(A @ W^T + bias)(+res)
// ---------------------------------------------------------------------------
template <int ACT, int RES, int OUTBF>
__global__ __launch_bounds__(256) void gemm_mfma(
    const u16* __restrict__ A, const u16* __restrict__ W,
    const float* __restrict__ bias, const float* __restrict__ res,
    void* __restrict__ Cout, int M, int N, int K)
{
    __shared__ u16 As[128 * 32];
    __shared__ u16 Bs[128 * 32];
    int t = threadIdx.x;
    int lane = t & 63;
    int w = t >> 6;
    int m0 = blockIdx.x * 128;
    int n0 = blockIdx.y * 128;
    int col = lane & 15;
    int quad = lane >> 4;
    int wm = w & 1, wn = w >> 1;

    const u16* ag = A + (size_t)(m0 + (t >> 2)) * K + (t & 3) * 8;
    const u16* ag2 = ag + (size_t)64 * K;
    const u16* bg = W + (size_t)(n0 + (t >> 2)) * K + (t & 3) * 8;
    const u16* bg2 = bg + (size_t)64 * K;
    u16* la = As + w * 512;
    u16* lb = Bs + w * 512;

    floatx4 acc[4][4];
#pragma unroll
    for (int i = 0; i < 4; i++)
#pragma unroll
        for (int j = 0; j < 4; j++) acc[i][j] = (floatx4){0.f, 0.f, 0.f, 0.f};

    for (int kt = 0; kt < K; kt += 32) {
        gload16(ag + kt, la);
        gload16(ag2 + kt, la + 2048);
        gload16(bg + kt, lb);
        gload16(bg2 + kt, lb + 2048);
        __syncthreads();
        short8 af[4], bf[4];
#pragma unroll
        for (int mi = 0; mi < 4; mi++)
            af[mi] = *(const short8*)&As[(wm * 64 + mi * 16 + col) * 32 + quad * 8];
#pragma unroll
        for (int ni = 0; ni < 4; ni++)
            bf[ni] = *(const short8*)&Bs[(wn * 64 + ni * 16 + col) * 32 + quad * 8];
#pragma unroll
        for (int mi = 0; mi < 4; mi++)
#pragma unroll
            for (int ni = 0; ni < 4; ni++)
                acc[mi][ni] = __builtin_amdgcn_mfma_f32_16x16x32_bf16(
                    af[mi], bf[ni], acc[mi][ni], 0, 0, 0);
        __syncthreads();
    }

#pragma unroll
    for (int mi = 0; mi < 4; mi++)
#pragma unroll
        for (int ni = 0; ni < 4; ni++) {
            int c = n0 + wn * 64 + ni * 16 + col;
            float bv = bias[c];
#pragma unroll
            for (int r = 0; r < 4; r++) {
                int m = m0 + wm * 64 + mi * 16 + quad * 4 + r;
                float v = acc[mi][ni][r] + bv;
                if (ACT == 1) v = 0.5f * v * (1.0f + erff(v * 0.70710678118654752f));
                if (RES) v += res[(size_t)m * N + c];
                if (OUTBF) ((u16*)Cout)[(size_t)m * N + c] = f2bf(v);
                else       ((float*)Cout)[(size_t)m * N + c] = v;
            }
        }
}

// ---------------------------------------------------------------------------
// bf16 MFMA GEMM, 64x128 tile — for N=512 layers (out-proj, FFN-down) where
// 128x128 gives only 256 blocks (1/CU). 512 blocks -> 2/CU.
// 4 waves; wave w owns N-quarter (2 ni frags), all 64 M rows (4 mi frags).
// ---------------------------------------------------------------------------
template <int ACT, int RES, int OUTBF>
__global__ __launch_bounds__(256) void gemm_mfma64(
    const u16* __restrict__ A, const u16* __restrict__ W,
    const float* __restrict__ bias, const float* __restrict__ res,
    void* __restrict__ Cout, int M, int N, int K)
{
    __shared__ u16 As[64 * 32];
    __shared__ u16 Bs[128 * 32];
    int t = threadIdx.x;
    int lane = t & 63;
    int w = t >> 6;
    int m0 = blockIdx.x * 64;
    int n0 = blockIdx.y * 128;
    int col = lane & 15;
    int quad = lane >> 4;

    const u16* ag = A + (size_t)(m0 + (t >> 2)) * K + (t & 3) * 8;
    const u16* bg = W + (size_t)(n0 + (t >> 2)) * K + (t & 3) * 8;
    const u16* bg2 = bg + (size_t)64 * K;
    u16* la = As + w * 512;
    u16* lb = Bs + w * 512;

    floatx4 acc[4][2];
#pragma unroll
    for (int i = 0; i < 4; i++)
#pragma unroll
        for (int j = 0; j < 2; j++) acc[i][j] = (floatx4){0.f, 0.f, 0.f, 0.f};

    for (int kt = 0; kt < K; kt += 32) {
        gload16(ag + kt, la);
        gload16(bg + kt, lb);
        gload16(bg2 + kt, lb + 2048);
        __syncthreads();
        short8 af[4], bf[2];
#pragma unroll
        for (int mi = 0; mi < 4; mi++)
            af[mi] = *(const short8*)&As[(mi * 16 + col) * 32 + quad * 8];
#pragma unroll
        for (int ni = 0; ni < 2; ni++)
            bf[ni] = *(const short8*)&Bs[(w * 32 + ni * 16 + col) * 32 + quad * 8];
#pragma unroll
        for (int mi = 0; mi < 4; mi++)
#pragma unroll
            for (int ni = 0; ni < 2; ni++)
                acc[mi][ni] = __builtin_amdgcn_mfma_f32_16x16x32_bf16(
                    af[mi], bf[ni], acc[mi][ni], 0, 0, 0);
        __syncthreads();
    }

#pragma unroll
    for (int mi = 0; mi < 4; mi++)
#pragma unroll
        for (int ni = 0; ni < 2; ni++) {
            int c = n0 + w * 32 + ni * 16 + col;
            float bv = bias[c];
#pragma unroll
            for (int r = 0; r < 4; r++) {
                int m = m0 + mi * 16 + quad * 4 + r;
                float v = acc[mi][ni][r] + bv;
                if (ACT == 1) v = 0.5f * v * (1.0f + erff(v * 0.70710678118654752f));
                if (RES) v += res[(size_t)m * N + c];
                if (OUTBF) ((u16*)Cout)[(size_t)m * N + c] = f2bf(v);
                else       ((float*)Cout)[(size_t)m * N + c] = v;
            }
        }
}

// ---------------------------------------------------------------------------
// V bf16 (in qkv [B,S,1536] @ col 1024..) -> vt bf16 [B,H,64,S] transposed
// ---------------------------------------------------------------------------
__global__ __launch_bounds__(256) void vt_kernel(
    const u16* __restrict__ qkvb, u16* __restrict__ vt)
{
    __shared__ u16 tile[64][72];
    int b = blockIdx.x >> 4;
    int s0 = (blockIdx.x & 15) * 64;
    int h = blockIdx.y;
    int t = threadIdx.x;
    int r = t >> 2;
    int c0 = (t & 3) * 16;
    const u16* src = qkvb + (size_t)(b * CS + s0 + r) * 1536 + 2 * CD + h * CHD + c0;
    *(ushort8v*)&tile[r][c0] = *(const ushort8v*)src;
    *(ushort8v*)&tile[r][c0 + 8] = *(const ushort8v*)(src + 8);
    __syncthreads();
    u16* dst = vt + (((size_t)b * CH + h) * CHD + r) * CS + s0 + c0;
    ushort8v lo, hi;
#pragma unroll
    for (int j = 0; j < 8; j++) { lo[j] = tile[c0 + j][r]; hi[j] = tile[c0 + 8 + j][r]; }
    *(ushort8v*)dst = lo;
    *(ushort8v*)(dst + 8) = hi;
}

// ---------------------------------------------------------------------------
// MFMA attention, round-4 dataflow at 2x waves. Block = (b, 16 q rows),
// 512 threads / 8 waves, loops 8 heads; grid 512 -> 2 blocks/CU, 16 waves/CU.
// QK pass: all 8 waves, wave w owns keys [w*128,+128): MFMA -> e=exp(s/8) ->
//   packed-pair bf16 store to S[16][1032]; rowsum partials (shfl) -> rs[8][16].
// barrier. Then concurrently:
//   waves 0-3: PV MFMA (wave w owns d-subtile w*16; P A-frags from S, V^T
//              B-frags 16B-contig from vt), O *= 1/L, ctx bf16.
//   waves 4-7: aw += p/8 from S (64 cells/thread, VGPR-resident across heads).
// barrier (S/rs reuse). 2 barriers/head, one QK pass, no scratch detour.
// ---------------------------------------------------------------------------
__global__ __launch_bounds__(512, 4) void attn_mfma_kernel(
    const u16* __restrict__ qkvb, const u16* __restrict__ vt,
    u16* __restrict__ ctx, float* __restrict__ aw_out)
{
    __shared__ u16 S[16][1032];
    __shared__ float rs[8][16];

    int tid = threadIdx.x;
    int lane = tid & 63;
    int w = tid >> 6;          // wave 0..7
    int b = blockIdx.x >> 6;
    int q0 = (blockIdx.x & 63) * 16;
    int col = lane & 15;
    int quad = lane >> 4;
    int ut = tid & 255;        // index within wave-group of 4
    int qo = ut & 15;          // aw q ownership (waves 4-7)
    int kc = ut >> 4;          // aw key-chunk ownership 0..15

    float aw[64];
#pragma unroll
    for (int i = 0; i < 64; i++) aw[i] = 0.f;

    const u16* qkb = qkvb + (size_t)b * CS * 1536;

    for (int h = 0; h < CH; h++) {
        // Q A-fragments (two d-halves), straight from global
        const u16* qrow = qkb + (size_t)(q0 + col) * 1536 + h * CHD + quad * 8;
        short8 qa0 = *(const short8*)qrow;
        short8 qa1 = *(const short8*)(qrow + 32);

        // ---- QK pass: e = exp(s/8) -> S, partial rowsums ----
        float esum[4] = {0.f, 0.f, 0.f, 0.f};
#pragma unroll
        for (int st = 0; st < 8; st++) {
            int key0 = w * 128 + st * 16;
            const u16* krow = qkb + (size_t)(key0 + col) * 1536 + CD + h * CHD + quad * 8;
            short8 kb0 = *(const short8*)krow;
            short8 kb1 = *(const short8*)(krow + 32);
            floatx4 c = {0.f, 0.f, 0.f, 0.f};
            c = __builtin_amdgcn_mfma_f32_16x16x32_bf16(qa0, kb0, c, 0, 0, 0);
            c = __builtin_amdgcn_mfma_f32_16x16x32_bf16(qa1, kb1, c, 0, 0, 0);
#pragma unroll
            for (int r = 0; r < 4; r++) {
                float e = __expf(c[r] * 0.125f);
                esum[r] += e;
                float o = __shfl_xor(e, 1, 64);
                if ((lane & 1) == 0) {
                    union { float f; u32 u; } eu, ou;
                    eu.f = e; ou.f = o;
                    u32 pk = __builtin_amdgcn_perm(ou.u, eu.u, 0x07060302u);
                    *(u32*)&S[quad * 4 + r][key0 + col] = pk;
                }
            }
        }
#pragma unroll
        for (int r = 0; r < 4; r++) {
            esum[r] += __shfl_xor(esum[r], 1, 64);
            esum[r] += __shfl_xor(esum[r], 2, 64);
            esum[r] += __shfl_xor(esum[r], 4, 64);
            esum[r] += __shfl_xor(esum[r], 8, 64);
        }
        if (col == 0) {
#pragma unroll
            for (int r = 0; r < 4; r++) rs[w][quad * 4 + r] = esum[r];
        }
        __syncthreads();

        if (w < 4) {
            // ---- PV (waves 0-3): wave w owns d-subtile [w*16, +16) ----
            float li[4];
#pragma unroll
            for (int r = 0; r < 4; r++) {
                int row = quad * 4 + r;
                float L = 0.f;
#pragma unroll
                for (int j = 0; j < 8; j++) L += rs[j][row];
                li[r] = 1.0f / L;
            }
            floatx4 oc0 = {0.f, 0.f, 0.f, 0.f};
            floatx4 oc1 = {0.f, 0.f, 0.f, 0.f};
            const u16* vrow = vt + (((size_t)b * CH + h) * CHD + w * 16 + col) * CS + quad * 8;
#pragma unroll 4
            for (int cix = 0; cix < 32; cix += 2) {
                short8 pa0 = *(const short8*)&S[col][cix * 32 + quad * 8];
                short8 vb0 = *(const short8*)(vrow + cix * 32);
                oc0 = __builtin_amdgcn_mfma_f32_16x16x32_bf16(pa0, vb0, oc0, 0, 0, 0);
                short8 pa1 = *(const short8*)&S[col][(cix + 1) * 32 + quad * 8];
                short8 vb1 = *(const short8*)(vrow + (cix + 1) * 32);
                oc1 = __builtin_amdgcn_mfma_f32_16x16x32_bf16(pa1, vb1, oc1, 0, 0, 0);
            }
            u16* cb = ctx + ((size_t)(b * CS) + q0) * CD + h * CHD + w * 16 + col;
#pragma unroll
            for (int r = 0; r < 4; r++)
                cb[(size_t)(quad * 4 + r) * CD] = f2bf((oc0[r] + oc1[r]) * li[r]);
        } else {
            // ---- aw accumulation (waves 4-7), read-only from S ----
            float L = 0.f;
#pragma unroll
            for (int j = 0; j < 8; j++) L += rs[j][qo];
            float liq = 0.125f / L;
#pragma unroll
            for (int i = 0; i < 16; i++) {
                int key = kc * 4 + i * 64;
                ushort4 sv = *(const ushort4*)&S[qo][key];
                aw[i * 4 + 0] += bf2f(sv.x) * liq;
                aw[i * 4 + 1] += bf2f(sv.y) * liq;
                aw[i * 4 + 2] += bf2f(sv.z) * liq;
                aw[i * 4 + 3] += bf2f(sv.w) * liq;
            }
        }
        __syncthreads();   // S, rs reused next head
    }

    if (w >= 4) {
        float* awp = aw_out + ((size_t)(b * CS) + q0 + qo) * CS + kc * 4;
#pragma unroll
        for (int i = 0; i < 16; i++)
            *(float4*)(awp + i * 64) =
                make_float4(aw[i * 4], aw[i * 4 + 1], aw[i * 4 + 2], aw[i * 4 + 3]);
    }
}

// ---------------------------------------------------------------------------
extern "C" void kernel_launch(void* const* d_in, const int* in_sizes, int n_in,
                              void* d_out, int out_size, void* d_ws, size_t ws_size,
                              hipStream_t stream)
{
    const float* x    = (const float*)d_in[0];
    const int*   ids  = (const int*)d_in[1];
    const float* emb  = (const float*)d_in[2];
    const float* inw  = (const float*)d_in[3];
    const float* inb  = (const float*)d_in[4];
    const float* ow   = (const float*)d_in[5];
    const float* ob   = (const float*)d_in[6];
    const float* g1   = (const float*)d_in[7];
    const float* be1  = (const float*)d_in[8];
    const float* g2   = (const float*)d_in[9];
    const float* be2  = (const float*)d_in[10];
    const float* w1   = (const float*)d_in[11];
    const float* b1   = (const float*)d_in[12];
    const float* w2   = (const float*)d_in[13];
    const float* b2   = (const float*)d_in[14];

    float* out_x  = (float*)d_out;
    float* out_aw = out_x + (size_t)CB * CS * CD;

    char* p = (char*)d_ws;
    float* xr   = (float*)p; p += (size_t)NROW * CD * 4;              // 16 MB
    float* x2   = (float*)p; p += (size_t)NROW * CD * 4;              // 16 MB
    u16* xnb    = (u16*)p;   p += (size_t)NROW * CD * 2;              //  8 MB
    u16* qkvb   = (u16*)p;   p += (size_t)NROW * 3 * CD * 2;          // 24 MB
    u16* ctxb   = (u16*)p;   p += (size_t)NROW * CD * 2;              //  8 MB
    u16* hidb   = (u16*)p;   p += (size_t)NROW * CDFF * 2;            // 32 MB
    u16* vtb    = (u16*)p;   p += (size_t)CB * CH * CHD * CS * 2;     // 16 MB
    u16* inwb   = (u16*)p;   p += (size_t)3 * CD * CD * 2;
    u16* owb    = (u16*)p;   p += (size_t)CD * CD * 2;
    u16* w1b    = (u16*)p;   p += (size_t)CDFF * CD * 2;
    u16* w2b    = (u16*)p;   p += (size_t)CD * CDFF * 2;

    dim3 blk(256);
    // 0) weight conversions
    conv_kernel<<<(3 * CD * CD) / 2048, blk, 0, stream>>>(inw, inwb);
    conv_kernel<<<(CD * CD) / 2048, blk, 0, stream>>>(ow, owb);
    conv_kernel<<<(CDFF * CD) / 2048, blk, 0, stream>>>(w1, w1b);
    conv_kernel<<<(CD * CDFF) / 2048, blk, 0, stream>>>(w2, w2b);
    // 1) x+emb, LN1 -> xr fp32, xnb bf16
    ln_kernel<<<NROW, blk, 0, stream>>>(x, ids, emb, g1, be1, xr, xnb);
    // 2) qkv projection (bf16 MFMA, bf16 out)
    gemm_mfma<0, 0, 1><<<dim3(NROW / 128, (3 * CD) / 128), blk, 0, stream>>>(
        xnb, inwb, inb, nullptr, qkvb, NROW, 3 * CD, CD);
    // 3a) V transpose
    vt_kernel<<<dim3(CB * (CS / 64), CH), blk, 0, stream>>>(qkvb, vtb);
    // 3b) attention -> ctx bf16 + averaged weights (512 threads, 8 waves)
    attn_mfma_kernel<<<CB * (CS / 16), dim3(512), 0, stream>>>(
        qkvb, vtb, ctxb, out_aw);
    // 4) out projection + residual -> x2 fp32 (64x128 tiles: 512 blocks)
    gemm_mfma64<0, 1, 0><<<dim3(NROW / 64, CD / 128), blk, 0, stream>>>(
        ctxb, owb, ob, xr, x2, NROW, CD, CD);
    // 5) LN2 -> xnb bf16
    ln_kernel<<<NROW, blk, 0, stream>>>(x2, nullptr, nullptr, g2, be2, nullptr, xnb);
    // 6) FFN up + exact GELU -> hidb bf16
    gemm_mfma<1, 0, 1><<<dim3(NROW / 128, CDFF / 128), blk, 0, stream>>>(
        xnb, w1b, b1, nullptr, hidb, NROW, CDFF, CD);
    // 7) FFN down + bias + residual -> output fp32 (64x128 tiles: 512 blocks)
    gemm_mfma64<0, 1, 0><<<dim3(NROW / 64, CD / 128), blk, 0, stream>>>(
        hidb, w2b, b2, x2, out_x, NROW, CD, CDFF);
}

// Round 7
// 375.658 us; speedup vs baseline: 1.1955x; 1.0960x over previous
//
#include <hip/hip_runtime.h>
#include <math.h>

// Problem constants
constexpr int CB = 8;      // batch
constexpr int CS = 1024;   // seq
constexpr int CD = 512;    // model dim
constexpr int CH = 8;      // heads
constexpr int CHD = 64;    // head dim
constexpr int CDFF = 2048; // ffn dim
constexpr int NROW = CB * CS;

typedef unsigned short u16;
typedef unsigned int u32;
typedef __attribute__((ext_vector_type(8))) short short8;
typedef __attribute__((ext_vector_type(8))) unsigned short ushort8v;
typedef __attribute__((ext_vector_type(4))) float floatx4;

__device__ inline u16 f2bf(float f) {
    union { float f; unsigned u; } v; v.f = f;
    unsigned u = v.u + 0x7FFFu + ((v.u >> 16) & 1u);  // RNE
    return (u16)(u >> 16);
}
__device__ inline float bf2f(u16 h) {
    union { unsigned u; float f; } v; v.u = ((unsigned)h) << 16;
    return v.f;
}

// async global->LDS, 16B per lane; LDS dest is wave-uniform base + lane*16
__device__ inline void gload16(const u16* g, u16* l) {
    __builtin_amdgcn_global_load_lds(
        (const __attribute__((address_space(1))) u32*)g,
        (__attribute__((address_space(3))) u32*)l, 16, 0, 0);
}

// ---------------------------------------------------------------------------
// LayerNorm (+ optional embedding add). One block per row, 256 threads.
// ---------------------------------------------------------------------------
__global__ __launch_bounds__(256) void ln_kernel(
    const float* __restrict__ x, const int* __restrict__ ids,
    const float* __restrict__ emb,
    const float* __restrict__ g, const float* __restrict__ beta,
    float* __restrict__ xr_out, u16* __restrict__ xn_out)
{
    __shared__ float red1[4], red2[4];
    __shared__ float mu_s, ri_s;
    int row = blockIdx.x;
    int tid = threadIdx.x;
    int d0 = tid * 2;
    const float* xrow = x + (size_t)row * CD;
    float2 xv = *(const float2*)(xrow + d0);
    float v0 = xv.x, v1 = xv.y;
    if (emb) {
        int id = ids[row];
        float2 ev = *(const float2*)(emb + (size_t)id * CD + d0);
        v0 += ev.x; v1 += ev.y;
    }
    float s1 = v0 + v1;
    float s2 = v0 * v0 + v1 * v1;
    for (int off = 32; off > 0; off >>= 1) {
        s1 += __shfl_down(s1, off, 64);
        s2 += __shfl_down(s2, off, 64);
    }
    int wave = tid >> 6;
    if ((tid & 63) == 0) { red1[wave] = s1; red2[wave] = s2; }
    __syncthreads();
    if (tid == 0) {
        float t1 = red1[0] + red1[1] + red1[2] + red1[3];
        float t2 = red2[0] + red2[1] + red2[2] + red2[3];
        float mu = t1 / CD;
        float var = t2 / CD - mu * mu;
        mu_s = mu;
        ri_s = rsqrtf(var + 1e-5f);
    }
    __syncthreads();
    float mu = mu_s, ri = ri_s;
    if (xr_out) {
        float2 o; o.x = v0; o.y = v1;
        *(float2*)(xr_out + (size_t)row * CD + d0) = o;
    }
    float2 gv = *(const float2*)(g + d0);
    float2 bv = *(const float2*)(beta + d0);
    float n0 = (v0 - mu) * ri * gv.x + bv.x;
    float n1 = (v1 - mu) * ri * gv.y + bv.y;
    u32 pk = (u32)f2bf(n0) | ((u32)f2bf(n1) << 16);
    *(u32*)(xn_out + (size_t)row * CD + d0) = pk;
}

// ---------------------------------------------------------------------------
// fp32 -> bf16 elementwise convert (weights), 8 elems/thread
// ---------------------------------------------------------------------------
__global__ __launch_bounds__(256) void conv_kernel(
    const float* __restrict__ src, u16* __restrict__ dst)
{
    size_t i = ((size_t)blockIdx.x * 256 + threadIdx.x) * 8;
    float4 a = *(const float4*)(src + i);
    float4 b = *(const float4*)(src + i + 4);
    ushort8v o;
    o[0] = f2bf(a.x); o[1] = f2bf(a.y); o[2] = f2bf(a.z); o[3] = f2bf(a.w);
    o[4] = f2bf(b.x); o[5] = f2bf(b.y); o[6] = f2bf(b.z); o[7] = f2bf(b.w);
    *(ushort8v*)(dst + i) = o;
}

// ---------------------------------------------------------------------------
// bf16 MFMA GEMM, 128x128 tile (m97 recipe): C = act(A @ W^T + bias)(+res)
// ---------------------------------------------------------------------------
template <int ACT, int RES, int OUTBF>
__global__ __launch_bounds__(256) void gemm_mfma(
    const u16* __restrict__ A, const u16* __restrict__ W,
    const float* __restrict__ bias, const float* __restrict__ res,
    void* __restrict__ Cout, int M, int N, int K)
{
    __shared__ u16 As[128 * 32];
    __shared__ u16 Bs[128 * 32];
    int t = threadIdx.x;
    int lane = t & 63;
    int w = t >> 6;
    int m0 = blockIdx.x * 128;
    int n0 = blockIdx.y * 128;
    int col = lane & 15;
    int quad = lane >> 4;
    int wm = w & 1, wn = w >> 1;

    const u16* ag = A + (size_t)(m0 + (t >> 2)) * K + (t & 3) * 8;
    const u16* ag2 = ag + (size_t)64 * K;
    const u16* bg = W + (size_t)(n0 + (t >> 2)) * K + (t & 3) * 8;
    const u16* bg2 = bg + (size_t)64 * K;
    u16* la = As + w * 512;
    u16* lb = Bs + w * 512;

    floatx4 acc[4][4];
#pragma unroll
    for (int i = 0; i < 4; i++)
#pragma unroll
        for (int j = 0; j < 4; j++) acc[i][j] = (floatx4){0.f, 0.f, 0.f, 0.f};

    for (int kt = 0; kt < K; kt += 32) {
        gload16(ag + kt, la);
        gload16(ag2 + kt, la + 2048);
        gload16(bg + kt, lb);
        gload16(bg2 + kt, lb + 2048);
        __syncthreads();
        short8 af[4], bf[4];
#pragma unroll
        for (int mi = 0; mi < 4; mi++)
            af[mi] = *(const short8*)&As[(wm * 64 + mi * 16 + col) * 32 + quad * 8];
#pragma unroll
        for (int ni = 0; ni < 4; ni++)
            bf[ni] = *(const short8*)&Bs[(wn * 64 + ni * 16 + col) * 32 + quad * 8];
#pragma unroll
        for (int mi = 0; mi < 4; mi++)
#pragma unroll
            for (int ni = 0; ni < 4; ni++)
                acc[mi][ni] = __builtin_amdgcn_mfma_f32_16x16x32_bf16(
                    af[mi], bf[ni], acc[mi][ni], 0, 0, 0);
        __syncthreads();
    }

#pragma unroll
    for (int mi = 0; mi < 4; mi++)
#pragma unroll
        for (int ni = 0; ni < 4; ni++) {
            int c = n0 + wn * 64 + ni * 16 + col;
            float bv = bias[c];
#pragma unroll
            for (int r = 0; r < 4; r++) {
                int m = m0 + wm * 64 + mi * 16 + quad * 4 + r;
                float v = acc[mi][ni][r] + bv;
                if (ACT == 1) v = 0.5f * v * (1.0f + erff(v * 0.70710678118654752f));
                if (RES) v += res[(size_t)m * N + c];
                if (OUTBF) ((u16*)Cout)[(size_t)m * N + c] = f2bf(v);
                else       ((float*)Cout)[(size_t)m * N + c] = v;
            }
        }
}

// ---------------------------------------------------------------------------
// bf16 MFMA GEMM, 64x128 tile — for N=512 layers (512 blocks -> 2/CU)
// ---------------------------------------------------------------------------
template <int ACT, int RES, int OUTBF>
__global__ __launch_bounds__(256) void gemm_mfma64(
    const u16* __restrict__ A, const u16* __restrict__ W,
    const float* __restrict__ bias, const float* __restrict__ res,
    void* __restrict__ Cout, int M, int N, int K)
{
    __shared__ u16 As[64 * 32];
    __shared__ u16 Bs[128 * 32];
    int t = threadIdx.x;
    int lane = t & 63;
    int w = t >> 6;
    int m0 = blockIdx.x * 64;
    int n0 = blockIdx.y * 128;
    int col = lane & 15;
    int quad = lane >> 4;

    const u16* ag = A + (size_t)(m0 + (t >> 2)) * K + (t & 3) * 8;
    const u16* bg = W + (size_t)(n0 + (t >> 2)) * K + (t & 3) * 8;
    const u16* bg2 = bg + (size_t)64 * K;
    u16* la = As + w * 512;
    u16* lb = Bs + w * 512;

    floatx4 acc[4][2];
#pragma unroll
    for (int i = 0; i < 4; i++)
#pragma unroll
        for (int j = 0; j < 2; j++) acc[i][j] = (floatx4){0.f, 0.f, 0.f, 0.f};

    for (int kt = 0; kt < K; kt += 32) {
        gload16(ag + kt, la);
        gload16(bg + kt, lb);
        gload16(bg2 + kt, lb + 2048);
        __syncthreads();
        short8 af[4], bf[2];
#pragma unroll
        for (int mi = 0; mi < 4; mi++)
            af[mi] = *(const short8*)&As[(mi * 16 + col) * 32 + quad * 8];
#pragma unroll
        for (int ni = 0; ni < 2; ni++)
            bf[ni] = *(const short8*)&Bs[(w * 32 + ni * 16 + col) * 32 + quad * 8];
#pragma unroll
        for (int mi = 0; mi < 4; mi++)
#pragma unroll
            for (int ni = 0; ni < 2; ni++)
                acc[mi][ni] = __builtin_amdgcn_mfma_f32_16x16x32_bf16(
                    af[mi], bf[ni], acc[mi][ni], 0, 0, 0);
        __syncthreads();
    }

#pragma unroll
    for (int mi = 0; mi < 4; mi++)
#pragma unroll
        for (int ni = 0; ni < 2; ni++) {
            int c = n0 + w * 32 + ni * 16 + col;
            float bv = bias[c];
#pragma unroll
            for (int r = 0; r < 4; r++) {
                int m = m0 + mi * 16 + quad * 4 + r;
                float v = acc[mi][ni][r] + bv;
                if (ACT == 1) v = 0.5f * v * (1.0f + erff(v * 0.70710678118654752f));
                if (RES) v += res[(size_t)m * N + c];
                if (OUTBF) ((u16*)Cout)[(size_t)m * N + c] = f2bf(v);
                else       ((float*)Cout)[(size_t)m * N + c] = v;
            }
        }
}

// ---------------------------------------------------------------------------
// V bf16 (in qkv [B,S,1536] @ col 1024..) -> vt bf16 [B,H,64,S] transposed
// ---------------------------------------------------------------------------
__global__ __launch_bounds__(256) void vt_kernel(
    const u16* __restrict__ qkvb, u16* __restrict__ vt)
{
    __shared__ u16 tile[64][72];
    int b = blockIdx.x >> 4;
    int s0 = (blockIdx.x & 15) * 64;
    int h = blockIdx.y;
    int t = threadIdx.x;
    int r = t >> 2;
    int c0 = (t & 3) * 16;
    const u16* src = qkvb + (size_t)(b * CS + s0 + r) * 1536 + 2 * CD + h * CHD + c0;
    *(ushort8v*)&tile[r][c0] = *(const ushort8v*)src;
    *(ushort8v*)&tile[r][c0 + 8] = *(const ushort8v*)(src + 8);
    __syncthreads();
    u16* dst = vt + (((size_t)b * CH + h) * CHD + r) * CS + s0 + c0;
    ushort8v lo, hi;
#pragma unroll
    for (int j = 0; j < 8; j++) { lo[j] = tile[c0 + j][r]; hi[j] = tile[c0 + 8 + j][r]; }
    *(ushort8v*)dst = lo;
    *(ushort8v*)(dst + 8) = hi;
}

// ---------------------------------------------------------------------------
// MFMA attention v7. Block = (b, 16 q rows), 512 threads / 8 waves, loops 8
// heads; grid 512 -> 2 blocks/CU, 16 waves/CU. All work split 8 ways, aw
// spread over ALL threads (32 floats/thread -> no spill).
//   QK: wave w keys [w*128,+128): MFMA -> e=exp(s/8) -> ds_write_b16 to
//       S[par] (no shfl/perm packing); rowsum partials -> rs[par][8][16].
//   barrier A. All threads: aw += p/8 (32 cells: q=tid&15, kc=tid>>4).
//   PV: wave w: d-subtile (w&3), key-half (w>>2)*512; 16 MFMA into 2 accs.
//   waves 4-7 park partial O in Oex; barrier B; waves 0-3 combine + 1/L
//   scale -> ctx bf16. S/rs parity-double-buffered => 2 barriers/head.
// ---------------------------------------------------------------------------
__global__ __launch_bounds__(512, 4) void attn_mfma_kernel(
    const u16* __restrict__ qkvb, const u16* __restrict__ vt,
    u16* __restrict__ ctx, float* __restrict__ aw_out)
{
    __shared__ u16 S[2][16][1032];
    __shared__ float rs[2][8][16];
    __shared__ float Oex[4][64][4];

    int tid = threadIdx.x;
    int lane = tid & 63;
    int w = tid >> 6;          // wave 0..7
    int b = blockIdx.x >> 6;
    int q0 = (blockIdx.x & 63) * 16;
    int col = lane & 15;
    int quad = lane >> 4;
    int qo = tid & 15;         // aw q ownership
    int kc = tid >> 4;         // aw key-chunk ownership 0..31
    int dsub = w & 3;          // PV d-subtile
    int khalf = w >> 2;        // PV key half

    float aw[32];
#pragma unroll
    for (int i = 0; i < 32; i++) aw[i] = 0.f;

    const u16* qkb = qkvb + (size_t)b * CS * 1536;

    for (int h = 0; h < CH; h++) {
        int par = h & 1;
        // Q A-fragments (two d-halves), straight from global
        const u16* qrow = qkb + (size_t)(q0 + col) * 1536 + h * CHD + quad * 8;
        short8 qa0 = *(const short8*)qrow;
        short8 qa1 = *(const short8*)(qrow + 32);

        // ---- QK: e = exp(s/8) -> S[par], partial rowsums ----
        float esum[4] = {0.f, 0.f, 0.f, 0.f};
#pragma unroll
        for (int st = 0; st < 8; st++) {
            int key0 = w * 128 + st * 16;
            const u16* krow = qkb + (size_t)(key0 + col) * 1536 + CD + h * CHD + quad * 8;
            short8 kb0 = *(const short8*)krow;
            short8 kb1 = *(const short8*)(krow + 32);
            floatx4 c = {0.f, 0.f, 0.f, 0.f};
            c = __builtin_amdgcn_mfma_f32_16x16x32_bf16(qa0, kb0, c, 0, 0, 0);
            c = __builtin_amdgcn_mfma_f32_16x16x32_bf16(qa1, kb1, c, 0, 0, 0);
#pragma unroll
            for (int r = 0; r < 4; r++) {
                float e = __expf(c[r] * 0.125f);
                esum[r] += e;
                union { float f; u32 u; } pu; pu.f = e;
                S[par][quad * 4 + r][key0 + col] = (u16)(pu.u >> 16);  // bf16 trunc
            }
        }
#pragma unroll
        for (int r = 0; r < 4; r++) {
            esum[r] += __shfl_xor(esum[r], 1, 64);
            esum[r] += __shfl_xor(esum[r], 2, 64);
            esum[r] += __shfl_xor(esum[r], 4, 64);
            esum[r] += __shfl_xor(esum[r], 8, 64);
        }
        if (col == 0) {
#pragma unroll
            for (int r = 0; r < 4; r++) rs[par][w][quad * 4 + r] = esum[r];
        }
        __syncthreads();   // barrier A: S[par], rs[par] complete

        // ---- aw accumulation: all 512 threads, 32 cells each ----
        {
            float L = 0.f;
#pragma unroll
            for (int j = 0; j < 8; j++) L += rs[par][j][qo];
            float liq = 0.125f / L;
#pragma unroll
            for (int i = 0; i < 8; i++) {
                int key = kc * 4 + i * 128;
                ushort4 sv = *(const ushort4*)&S[par][qo][key];
                aw[i * 4 + 0] += bf2f(sv.x) * liq;
                aw[i * 4 + 1] += bf2f(sv.y) * liq;
                aw[i * 4 + 2] += bf2f(sv.z) * liq;
                aw[i * 4 + 3] += bf2f(sv.w) * liq;
            }
        }

        // ---- PV: wave w -> d-subtile dsub, keys [khalf*512, +512) ----
        floatx4 oc0 = {0.f, 0.f, 0.f, 0.f};
        floatx4 oc1 = {0.f, 0.f, 0.f, 0.f};
        const u16* vrow = vt + (((size_t)b * CH + h) * CHD + dsub * 16 + col) * CS
                          + khalf * 512 + quad * 8;
#pragma unroll
        for (int kt = 0; kt < 8; kt++) {
            int key0 = khalf * 512 + kt * 64;
            short8 pa0 = *(const short8*)&S[par][col][key0 + quad * 8];
            short8 vb0 = *(const short8*)(vrow + kt * 64);
            oc0 = __builtin_amdgcn_mfma_f32_16x16x32_bf16(pa0, vb0, oc0, 0, 0, 0);
            short8 pa1 = *(const short8*)&S[par][col][key0 + 32 + quad * 8];
            short8 vb1 = *(const short8*)(vrow + kt * 64 + 32);
            oc1 = __builtin_amdgcn_mfma_f32_16x16x32_bf16(pa1, vb1, oc1, 0, 0, 0);
        }
        if (w >= 4) {
            Oex[dsub][lane][0] = oc0[0] + oc1[0];
            Oex[dsub][lane][1] = oc0[1] + oc1[1];
            Oex[dsub][lane][2] = oc0[2] + oc1[2];
            Oex[dsub][lane][3] = oc0[3] + oc1[3];
        }
        __syncthreads();   // barrier B: Oex complete
        if (w < 4) {
            float li[4];
#pragma unroll
            for (int r = 0; r < 4; r++) {
                int row = quad * 4 + r;
                float L = 0.f;
#pragma unroll
                for (int j = 0; j < 8; j++) L += rs[par][j][row];
                li[r] = 1.0f / L;
            }
            float4 op = *(const float4*)&Oex[dsub][lane][0];
            float po[4] = {op.x, op.y, op.z, op.w};
            u16* cb = ctx + ((size_t)(b * CS) + q0) * CD + h * CHD + dsub * 16 + col;
#pragma unroll
            for (int r = 0; r < 4; r++)
                cb[(size_t)(quad * 4 + r) * CD] = f2bf((oc0[r] + oc1[r] + po[r]) * li[r]);
        }
        // no trailing barrier: next head uses S[par^1]/rs[par^1]; Oex reuse is
        // protected by next head's barrier A (combine precedes it program-order).
    }

    // write head-averaged attention weights: thread owns (qo, kc*4 + i*128 +j)
    float* awp = aw_out + ((size_t)(b * CS) + q0 + qo) * CS + kc * 4;
#pragma unroll
    for (int i = 0; i < 8; i++)
        *(float4*)(awp + i * 128) =
            make_float4(aw[i * 4], aw[i * 4 + 1], aw[i * 4 + 2], aw[i * 4 + 3]);
}

// ---------------------------------------------------------------------------
extern "C" void kernel_launch(void* const* d_in, const int* in_sizes, int n_in,
                              void* d_out, int out_size, void* d_ws, size_t ws_size,
                              hipStream_t stream)
{
    const float* x    = (const float*)d_in[0];
    const int*   ids  = (const int*)d_in[1];
    const float* emb  = (const float*)d_in[2];
    const float* inw  = (const float*)d_in[3];
    const float* inb  = (const float*)d_in[4];
    const float* ow   = (const float*)d_in[5];
    const float* ob   = (const float*)d_in[6];
    const float* g1   = (const float*)d_in[7];
    const float* be1  = (const float*)d_in[8];
    const float* g2   = (const float*)d_in[9];
    const float* be2  = (const float*)d_in[10];
    const float* w1   = (const float*)d_in[11];
    const float* b1   = (const float*)d_in[12];
    const float* w2   = (const float*)d_in[13];
    const float* b2   = (const float*)d_in[14];

    float* out_x  = (float*)d_out;
    float* out_aw = out_x + (size_t)CB * CS * CD;

    char* p = (char*)d_ws;
    float* xr   = (float*)p; p += (size_t)NROW * CD * 4;
    float* x2   = (float*)p; p += (size_t)NROW * CD * 4;
    u16* xnb    = (u16*)p;   p += (size_t)NROW * CD * 2;
    u16* qkvb   = (u16*)p;   p += (size_t)NROW * 3 * CD * 2;
    u16* ctxb   = (u16*)p;   p += (size_t)NROW * CD * 2;
    u16* hidb   = (u16*)p;   p += (size_t)NROW * CDFF * 2;
    u16* vtb    = (u16*)p;   p += (size_t)CB * CH * CHD * CS * 2;
    u16* inwb   = (u16*)p;   p += (size_t)3 * CD * CD * 2;
    u16* owb    = (u16*)p;   p += (size_t)CD * CD * 2;
    u16* w1b    = (u16*)p;   p += (size_t)CDFF * CD * 2;
    u16* w2b    = (u16*)p;   p += (size_t)CD * CDFF * 2;

    dim3 blk(256);
    // 0) weight conversions
    conv_kernel<<<(3 * CD * CD) / 2048, blk, 0, stream>>>(inw, inwb);
    conv_kernel<<<(CD * CD) / 2048, blk, 0, stream>>>(ow, owb);
    conv_kernel<<<(CDFF * CD) / 2048, blk, 0, stream>>>(w1, w1b);
    conv_kernel<<<(CD * CDFF) / 2048, blk, 0, stream>>>(w2, w2b);
    // 1) x+emb, LN1 -> xr fp32, xnb bf16
    ln_kernel<<<NROW, blk, 0, stream>>>(x, ids, emb, g1, be1, xr, xnb);
    // 2) qkv projection (bf16 MFMA, bf16 out)
    gemm_mfma<0, 0, 1><<<dim3(NROW / 128, (3 * CD) / 128), blk, 0, stream>>>(
        xnb, inwb, inb, nullptr, qkvb, NROW, 3 * CD, CD);
    // 3a) V transpose
    vt_kernel<<<dim3(CB * (CS / 64), CH), blk, 0, stream>>>(qkvb, vtb);
    // 3b) attention -> ctx bf16 + averaged weights (512 threads, 8 waves)
    attn_mfma_kernel<<<CB * (CS / 16), dim3(512), 0, stream>>>(
        qkvb, vtb, ctxb, out_aw);
    // 4) out projection + residual -> x2 fp32 (64x128 tiles: 512 blocks)
    gemm_mfma64<0, 1, 0><<<dim3(NROW / 64, CD / 128), blk, 0, stream>>>(
        ctxb, owb, ob, xr, x2, NROW, CD, CD);
    // 5) LN2 -> xnb bf16
    ln_kernel<<<NROW, blk, 0, stream>>>(x2, nullptr, nullptr, g2, be2, nullptr, xnb);
    // 6) FFN up + exact GELU -> hidb bf16
    gemm_mfma<1, 0, 1><<<dim3(NROW / 128, CDFF / 128), blk, 0, stream>>>(
        xnb, w1b, b1, nullptr, hidb, NROW, CDFF, CD);
    // 7) FFN down + bias + residual -> output fp32 (64x128 tiles: 512 blocks)
    gemm_mfma64<0, 1, 0><<<dim3(NROW / 64, CD / 128), blk, 0, stream>>>(
        hidb, w2b, b2, x2, out_x, NROW, CD, CDFF);
}